// Round 3
// baseline (2111.148 us; speedup 1.0000x reference)
//
#include <hip/hip_runtime.h>
#include <hip/hip_bf16.h>
#include <math.h>

typedef unsigned short u16;
typedef short short8 __attribute__((ext_vector_type(8)));
typedef float floatx4 __attribute__((ext_vector_type(4)));

#define NB 128    // batch
#define NT 24     // time steps
#define NE 512    // embed dim
#define NH 512    // hidden dim
#define NR 512    // factor rank
#define NTAG 400  // tags
#define NV 20000  // vocab

__device__ __forceinline__ float bfu(u16 u) {
    unsigned x = ((unsigned)u) << 16;
    return __builtin_bit_cast(float, x);
}
__device__ __forceinline__ u16 f2b(float f) {
    unsigned u = __builtin_bit_cast(unsigned, f);
    unsigned r = (u + 0x7FFFu + ((u >> 16) & 1u)) >> 16;
    return (u16)r;
}
__device__ __forceinline__ float ldin(const void* p, long i, int f32) {
    return f32 ? ((const float*)p)[i] : bfu(((const u16*)p)[i]);
}

// Detect input dtype: fp32 data's low halves produce exponent-all-ones bf16
// patterns at p~1/256; true bf16 (scale 0.02) never does.
__global__ __launch_bounds__(256) void k_detect(const void* emb, int* flag) {
    __shared__ int cnt;
    if (threadIdx.x == 0) cnt = 0;
    __syncthreads();
    const u16* p = (const u16*)emb;
    int local = 0;
    for (int i = threadIdx.x; i < 65536; i += 256) {
        if ((p[i] & 0x7F80) == 0x7F80) local++;
    }
    atomicAdd(&cnt, local);
    __syncthreads();
    if (threadIdx.x == 0) *flag = (cnt > 4) ? 1 : 0;
}

// temp2[g][b][r] = sum_t s[b][t]*Wb[g][t][r] ; temp5 likewise with Ub
// Also zeroes the k_rec sync flags (stream-ordered before k_rec).
__global__ __launch_bounds__(256) void k_tags(const void* __restrict__ s,
        const void* __restrict__ Wb, const void* __restrict__ Ub,
        const int* __restrict__ flagp, float* __restrict__ temp2, float* __restrict__ temp5,
        int* __restrict__ flags) {
    if (blockIdx.x == 0 && threadIdx.x < 256) flags[threadIdx.x] = 0;
    int f32 = *flagp;
    int idx = blockIdx.x * 256 + threadIdx.x;      // over 4*NB*NR
    int r = idx & (NR - 1);
    int gb = idx >> 9;
    int b = gb & (NB - 1);
    int g = gb >> 7;
    float a2 = 0.f, a5 = 0.f;
    if (f32) {
        const float* srow = (const float*)s + b * NTAG;
        const float* wb = (const float*)Wb + (long)g * NTAG * NR + r;
        const float* ub = (const float*)Ub + (long)g * NTAG * NR + r;
        for (int t = 0; t < NTAG; t++) {
            float sv = srow[t];
            a2 += sv * wb[(long)t * NR];
            a5 += sv * ub[(long)t * NR];
        }
    } else {
        const u16* srow = (const u16*)s + b * NTAG;
        const u16* wb = (const u16*)Wb + (long)g * NTAG * NR + r;
        const u16* ub = (const u16*)Ub + (long)g * NTAG * NR + r;
        for (int t = 0; t < NTAG; t++) {
            float sv = bfu(srow[t]);
            a2 += sv * bfu(wb[(long)t * NR]);
            a5 += sv * bfu(ub[(long)t * NR]);
        }
    }
    temp2[idx] = a2;
    temp5[idx] = a5;
}

// Transpose + k-panel swizzle to bf16.
// Output layout (uint4-granular): US[((g*64 + kk)*512 + out)] holds 8 bf16,
// element j = U[g][kk*8 + j][out]  (U treated as [gate][in][out] row-major).
// This is exactly the MFMA B-fragment layout: lane (q,l15) of a k-step ks
// reads chunk (g*64 + ks*4 + q)*512 + n as a short8 -> B[k=ks*32+q*8+j][n].
// z = which*4 + g: which 0 -> Ua->UaS, which 1 -> Uc->UcS.
__global__ __launch_bounds__(256) void k_tr(const void* __restrict__ Ua,
        const void* __restrict__ Uc, const int* __restrict__ flagp,
        u16* __restrict__ UaS, u16* __restrict__ UcS) {
    int f32 = *flagp;
    int z = blockIdx.z;
    int which = z >> 2, g = z & 3;
    const void* src = which ? Uc : Ua;
    u16* dst = which ? UcS : UaS;
    __shared__ u16 tile[64][65];
    int i0 = blockIdx.x * 64;   // input (in-dim) row block
    int j0 = blockIdx.y * 64;   // input (out-dim) col block
    int t = threadIdx.x;
    int il = t >> 2, js = (t & 3) * 16;
    long base = ((long)g * 512 + i0 + il) * 512 + j0 + js;
    if (f32) {
        const float* q = (const float*)src + base;
        #pragma unroll
        for (int j = 0; j < 16; j++) tile[il][js + j] = f2b(q[j]);
    } else {
        const u16* q = (const u16*)src + base;
        #pragma unroll
        for (int j = 0; j < 16; j++) tile[il][js + j] = q[j];
    }
    __syncthreads();
    // store: 512 output 16B chunks per tile (8 k-panels x 64 out cols), 2/thread
    #pragma unroll
    for (int h = 0; h < 2; h++) {
        int idx = t + h * 256;
        int kl = idx >> 6, rl = idx & 63;
        u16 outv[8] __attribute__((aligned(16)));
        #pragma unroll
        for (int j = 0; j < 8; j++) outv[j] = tile[kl * 8 + j][rl];
        long ob = ((long)(g * 64 + (i0 >> 3) + kl) * 512 + (j0 + rl)) * 8;
        *(uint4*)(dst + ob) = *(uint4*)outv;
    }
}

// MFMA GEMM, block tile 64(M) x 128(N), K=512, 256 threads (4 waves).
// MODE 0: A = emb-gather (flag dtype), B = Wa[g] (flag), epi: *temp2 -> t1m bf16
// MODE 1: A = t1m[g] bf16, B = Wc[g] (flag), epi: plain -> gx bf16
// MODE 2: A = hs bf16, B = Wout (flag), epi: +bout, swizzle (t,b)->(b,t), guard n<NV
template<int MODE>
__global__ __launch_bounds__(256) void k_mfma(const void* __restrict__ Asrc,
        const void* __restrict__ Bsrc, void* __restrict__ dst,
        const int* __restrict__ captions, const float* __restrict__ temp2,
        const void* __restrict__ bout, const int* __restrict__ flagp) {
    const int f32 = *flagp;
    const int bm = blockIdx.x * 64;
    const int bn = blockIdx.y * 128;
    const int g = blockIdx.z;
    const int NN = (MODE == 2) ? NV : NR;
    const int ldb = (MODE == 2) ? NV : NR;
    __shared__ __align__(16) u16 As[64 * 40];
    __shared__ __align__(16) u16 Bs[32 * 132];
    const int tid = threadIdx.x;
    const int sam = tid >> 2, sak = (tid & 3) * 8;      // A staging: row, k-offset
    const int sbk = tid >> 3, sbn = (tid & 7) * 16;     // B staging: k-row, n-offset
    long arow = 0;
    int azero = 0;
    if (MODE == 0) {
        int mg = bm + sam, tt = mg >> 7, bb = mg & (NB - 1);
        if (tt == 0) azero = 1;
        else arow = (long)captions[bb * NT + tt - 1] * NE;
    } else if (MODE == 1) {
        arow = ((long)g * NT * NB + bm + sam) * NR;
    } else {
        arow = (long)(bm + sam) * NH;
    }
    long bbase;
    if (MODE == 2) bbase = bn + sbn;
    else bbase = (long)g * 512 * 512 + bn + sbn;
    const int bguard = (MODE == 2) && (bn + 128 > NN);

    const int wv = tid >> 6, ln = tid & 63;
    const int q = ln >> 4, l15 = ln & 15;
    floatx4 acc[4][2];
    #pragma unroll
    for (int i = 0; i < 4; i++)
        #pragma unroll
        for (int j = 0; j < 2; j++)
            #pragma unroll
            for (int r = 0; r < 4; r++) acc[i][j][r] = 0.f;

    for (int k0 = 0; k0 < 512; k0 += 32) {
        // ---- stage A (8 elems/thread) ----
        u16 ta[8] __attribute__((aligned(16)));
        if (MODE == 0) {
            if (azero) {
                #pragma unroll
                for (int j = 0; j < 8; j++) ta[j] = 0;
            } else if (f32) {
                const float* qa = (const float*)Asrc + arow + k0 + sak;
                #pragma unroll
                for (int j = 0; j < 8; j++) ta[j] = f2b(qa[j]);
            } else {
                *(uint4*)ta = *(const uint4*)((const u16*)Asrc + arow + k0 + sak);
            }
        } else {
            *(uint4*)ta = *(const uint4*)((const u16*)Asrc + arow + k0 + sak);
        }
        *(uint4*)&As[sam * 40 + sak] = *(uint4*)ta;
        // ---- stage B (16 elems/thread, natural [k][n]) ----
        u16 tb[16] __attribute__((aligned(16)));
        long be = bbase + (long)(k0 + sbk) * ldb;
        if (!bguard) {
            if (f32) {
                const float* qb = (const float*)Bsrc + be;
                #pragma unroll
                for (int j = 0; j < 16; j++) tb[j] = f2b(qb[j]);
            } else {
                *(uint4*)tb = *(const uint4*)((const u16*)Bsrc + be);
                *(uint4*)(tb + 8) = *(const uint4*)((const u16*)Bsrc + be + 8);
            }
        } else {
            #pragma unroll
            for (int j = 0; j < 16; j++) {
                int n = bn + sbn + j;
                tb[j] = (n < NN) ? (f32 ? f2b(((const float*)Bsrc)[be + j])
                                        : ((const u16*)Bsrc)[be + j]) : (u16)0;
            }
        }
        *(uint2*)&Bs[sbk * 132 + sbn]      = *(uint2*)tb;
        *(uint2*)&Bs[sbk * 132 + sbn + 4]  = *(uint2*)(tb + 4);
        *(uint2*)&Bs[sbk * 132 + sbn + 8]  = *(uint2*)(tb + 8);
        *(uint2*)&Bs[sbk * 132 + sbn + 12] = *(uint2*)(tb + 12);
        __syncthreads();
        // ---- fragments + MFMA ----
        short8 af[4];
        #pragma unroll
        for (int mi = 0; mi < 4; mi++)
            af[mi] = *(const short8*)&As[(mi * 16 + l15) * 40 + q * 8];
        #pragma unroll
        for (int ni = 0; ni < 2; ni++) {
            union { u16 u[8]; short8 v; } bu;
            int n = wv * 32 + ni * 16 + l15;
            #pragma unroll
            for (int j = 0; j < 8; j++) bu.u[j] = Bs[(q * 8 + j) * 132 + n];
            #pragma unroll
            for (int mi = 0; mi < 4; mi++)
                acc[mi][ni] = __builtin_amdgcn_mfma_f32_16x16x32_bf16(af[mi], bu.v, acc[mi][ni], 0, 0, 0);
        }
        __syncthreads();
    }
    // ---- epilogue ----
    #pragma unroll
    for (int mi = 0; mi < 4; mi++) {
        #pragma unroll
        for (int ni = 0; ni < 2; ni++) {
            int n = bn + wv * 32 + ni * 16 + l15;
            #pragma unroll
            for (int r = 0; r < 4; r++) {
                int m = bm + mi * 16 + q * 4 + r;
                float v = acc[mi][ni][r];
                if (MODE == 0) {
                    int bb = m & (NB - 1);
                    v *= temp2[((long)g * NB + bb) * NR + n];
                    ((u16*)dst)[((long)g * NT * NB + m) * NR + n] = f2b(v);
                } else if (MODE == 1) {
                    ((u16*)dst)[((long)g * NT * NB + m) * NR + n] = f2b(v);
                } else {
                    if (n < NV) {
                        int tt = m >> 7, bb = m & (NB - 1);
                        float o = v + ldin(bout, n, f32);
                        long oi = ((long)bb * NT + tt) * NV + n;
                        if (f32) ((float*)dst)[oi] = o;
                        else ((u16*)dst)[oi] = f2b(o);
                    }
                }
            }
        }
    }
}

// Recurrence as per-step batched MFMA GEMM.
// 128 blocks = 8 batch-groups(16 rows) x 4 gates x 4 col-slices(128), 512 thr.
// Phase A (replicated over the 4 c-siblings): t6[g][16][512] = (h @ Ua[g]) * t5,
//   MFMA M=16 N=512 K=512, B-frags direct from k-panel global, A from LDS h.
// Phase B: pre[g][16][c*128..+128] = t6 @ Uc[g] slice, published f32 via
//   agent-scope atomics (parity double-buffer) + monotone flag handshake
//   across the 16 blocks of the batch-group; pointwise LSTM redundant per
//   block (cstate in regs), h -> LDS for next step.
__global__ __launch_bounds__(512) void k_rec(const u16* __restrict__ UaS,
        const u16* __restrict__ UcS, const float* __restrict__ temp5,
        const u16* __restrict__ gx, const void* __restrict__ bias,
        const void* __restrict__ h0, const void* __restrict__ c0,
        const int* __restrict__ flagp, u16* __restrict__ hs,
        float* __restrict__ preX, int* __restrict__ flags) {
    const int f32 = *flagp;
    const int bid = blockIdx.x;
    const int bg = bid >> 4;           // batch group (16 rows)
    const int g  = (bid >> 2) & 3;     // gate
    const int c  = bid & 3;            // phase-B col slice (128)
    const int myid = g * 4 + c;
    const int tid = threadIdx.x;
    const int wv = tid >> 6, ln = tid & 63, q = ln >> 4, l15 = ln & 15;

    __shared__ __align__(16) u16 hb[16 * 520];   // h, bf16, padded rows
    __shared__ __align__(16) u16 t6s[16 * 520];  // t6, bf16, padded rows

    // pointwise mapping: thread owns (pb, pj..pj+15)
    const int pb = tid >> 5;
    const int pj = (tid & 31) * 16;
    const int bglob = bg * 16 + pb;
    float cs[16];
    #pragma unroll
    for (int j = 0; j < 16; j++) {
        hb[pb * 520 + pj + j] = f2b(ldin(h0, (long)bglob * NH + pj + j, f32));
        cs[j] = ldin(c0, (long)bglob * NH + pj + j, f32);
    }
    // temp5 in phase-A C-fragment layout: row b = q*4+r, col = wv*64+nt*16+l15
    float t5v[4][4];
    #pragma unroll
    for (int nt = 0; nt < 4; nt++)
        #pragma unroll
        for (int r = 0; r < 4; r++)
            t5v[nt][r] = temp5[((long)g * NB + bg * 16 + q * 4 + r) * NR
                               + wv * 64 + nt * 16 + l15];
    const bool own = (myid == (pj >> 5));
    __syncthreads();

    for (int t = 0; t < NT; t++) {
        const int pr_ = t & 1;
        // ---- phase A: t6 = (h @ Ua[g]) * t5 ; wave covers cols wv*64..+64 ----
        floatx4 accA[4];
        #pragma unroll
        for (int nt = 0; nt < 4; nt++)
            #pragma unroll
            for (int r = 0; r < 4; r++) accA[nt][r] = 0.f;
        const int colA = wv * 64 + l15;
        #pragma unroll 4
        for (int ks = 0; ks < 16; ks++) {
            short8 af = *(const short8*)&hb[l15 * 520 + ks * 32 + q * 8];
            #pragma unroll
            for (int nt = 0; nt < 4; nt++) {
                short8 bf = *(const short8*)(UaS
                    + ((long)(g * 64 + ks * 4 + q) * 512 + colA + nt * 16) * 8);
                accA[nt] = __builtin_amdgcn_mfma_f32_16x16x32_bf16(af, bf, accA[nt], 0, 0, 0);
            }
        }
        #pragma unroll
        for (int nt = 0; nt < 4; nt++)
            #pragma unroll
            for (int r = 0; r < 4; r++)
                t6s[(q * 4 + r) * 520 + colA + nt * 16] = f2b(accA[nt][r] * t5v[nt][r]);
        __syncthreads();
        // ---- phase B: pre slice = t6 @ Uc[g][:, c*128 + wv*16 + l15] ----
        floatx4 accB;
        #pragma unroll
        for (int r = 0; r < 4; r++) accB[r] = 0.f;
        const int colB = c * 128 + wv * 16 + l15;
        #pragma unroll 4
        for (int ks = 0; ks < 16; ks++) {
            short8 af = *(const short8*)&t6s[l15 * 520 + ks * 32 + q * 8];
            short8 bf = *(const short8*)(UcS
                + ((long)(g * 64 + ks * 4 + q) * 512 + colB) * 8);
            accB = __builtin_amdgcn_mfma_f32_16x16x32_bf16(af, bf, accB, 0, 0, 0);
        }
        // publish pre (f32, agent-scope atomics, parity buffer)
        float* pbase = preX + (((long)pr_ * 8 + bg) * 4 + g) * 16 * 512;
        #pragma unroll
        for (int r = 0; r < 4; r++)
            __hip_atomic_store(&pbase[(q * 4 + r) * 512 + colB], accB[r],
                               __ATOMIC_RELAXED, __HIP_MEMORY_SCOPE_AGENT);
        __syncthreads();   // all waves' stores drained (vmcnt0 before barrier)
        if (tid == 0)
            __hip_atomic_store(&flags[bg * 16 + myid], t + 1,
                               __ATOMIC_RELEASE, __HIP_MEMORY_SCOPE_AGENT);
        if (tid < 16)
            while (__hip_atomic_load(&flags[bg * 16 + tid],
                       __ATOMIC_RELAXED, __HIP_MEMORY_SCOPE_AGENT) < t + 1)
                __builtin_amdgcn_s_sleep(1);
        __syncthreads();
        __builtin_amdgcn_fence(__ATOMIC_ACQUIRE, "agent");
        // ---- pointwise LSTM (redundant across the 16 blocks of this bg) ----
        float pv[4][16];
        #pragma unroll
        for (int g4 = 0; g4 < 4; g4++) {
            const float* pbg = preX + ((((long)pr_ * 8 + bg) * 4 + g4) * 16 + pb) * 512 + pj;
            union { uint4 v[2]; u16 u[16]; } gxu;
            const u16* gp = gx + (((long)g4 * NT + t) * NB + bglob) * NH + pj;
            gxu.v[0] = *(const uint4*)gp;
            gxu.v[1] = *(const uint4*)(gp + 8);
            #pragma unroll
            for (int j = 0; j < 16; j++)
                pv[g4][j] = __hip_atomic_load(&pbg[j], __ATOMIC_RELAXED,
                                              __HIP_MEMORY_SCOPE_AGENT)
                            + bfu(gxu.u[j]) + ldin(bias, g4 * NH + pj + j, f32);
        }
        union { uint4 v[2]; u16 u[16]; } ho;
        #pragma unroll
        for (int j = 0; j < 16; j++) {
            float ig = 1.f / (1.f + expf(-pv[0][j]));
            float fg = 1.f / (1.f + expf(-pv[1][j]));
            float og = 1.f / (1.f + expf(-pv[2][j]));
            float ct = tanhf(pv[3][j]);
            float cn = fg * cs[j] + ig * ct;
            float hn = og * tanhf(cn);
            cs[j] = cn;
            ho.u[j] = f2b(hn);
        }
        *(uint4*)&hb[pb * 520 + pj]     = ho.v[0];
        *(uint4*)&hb[pb * 520 + pj + 8] = ho.v[1];
        if (own) {
            uint4* hp = (uint4*)&hs[((long)t * NB + bglob) * NH + pj];
            hp[0] = ho.v[0];
            hp[1] = ho.v[1];
        }
        __syncthreads();   // hb visible before next phase A
    }
}

extern "C" void kernel_launch(void* const* d_in, const int* in_sizes, int n_in,
                              void* d_out, int out_size, void* d_ws, size_t ws_size,
                              hipStream_t stream) {
    const int* captions = (const int*)d_in[0];
    const void* s    = d_in[1];
    const void* h0   = d_in[2];
    const void* c0   = d_in[3];
    const void* Wa   = d_in[4];
    const void* Wb   = d_in[5];
    const void* Wc   = d_in[6];
    const void* Ua   = d_in[7];
    const void* Ub   = d_in[8];
    const void* Uc   = d_in[9];
    const void* bias = d_in[10];
    const void* emb  = d_in[11];
    const void* Wout = d_in[12];
    const void* bout = d_in[13];

    // workspace (~33.3 MB)
    char* w = (char*)d_ws;
    int*   flag  = (int*)w;                                  // 256 B
    int*   flags = (int*)(w + 256);                          // 1 KB (256 ints)
    float* temp2 = (float*)(w + 2048);                       // 1 MB
    float* temp5 = temp2 + 4 * NB * NR;                      // 1 MB
    u16*   UaS   = (u16*)(temp5 + 4 * NB * NR);              // 2 MB bf16 (k-panel)
    u16*   UcS   = UaS + 4 * 512 * 512;                      // 2 MB bf16 (k-panel)
    u16*   t1m   = UcS + 4 * 512 * 512;                      // 12.6 MB bf16
    u16*   gx    = t1m + (long)4 * NT * NB * NR;             // 12.6 MB bf16
    float* preX  = (float*)(gx + (long)4 * NT * NB * NR);    // 2 MB (parity dbuf)
    u16*   hs    = t1m;  // alias: t1m dead after k_mfma<1>

    dim3 blk(256);
    k_detect<<<1, blk, 0, stream>>>(emb, flag);
    k_tags<<<(4 * NB * NR) / 256, blk, 0, stream>>>(s, Wb, Ub, flag, temp2, temp5, flags);
    k_tr<<<dim3(8, 8, 8), blk, 0, stream>>>(Ua, Uc, flag, UaS, UcS);

    // hoisted input path (MFMA)
    k_mfma<0><<<dim3(48, 4, 4), blk, 0, stream>>>(emb, Wa, t1m, captions, temp2, nullptr, flag);
    k_mfma<1><<<dim3(48, 4, 4), blk, 0, stream>>>(t1m, Wc, gx, nullptr, nullptr, nullptr, flag);

    // fused recurrence: 128 blocks (8 bg x 4 g x 4 c), MFMA + 1 exchange/step
    k_rec<<<128, 512, 0, stream>>>(UaS, UcS, temp5, gx, bias, h0, c0, flag, hs, preX, flags);

    // output projection (MFMA), grid.x = M-tiles so consecutive blocks share W strip in L2
    k_mfma<2><<<dim3(48, 157, 1), blk, 0, stream>>>(hs, Wout, d_out, nullptr, nullptr, bout, flag);
}

// Round 4
// 1367.789 us; speedup vs baseline: 1.5435x; 1.5435x over previous
//
#include <hip/hip_runtime.h>
#include <hip/hip_bf16.h>
#include <math.h>

typedef unsigned short u16;
typedef unsigned long long u64;
typedef short short8 __attribute__((ext_vector_type(8)));
typedef float floatx4 __attribute__((ext_vector_type(4)));

#define NB 128    // batch
#define NT 24     // time steps
#define NE 512    // embed dim
#define NH 512    // hidden dim
#define NR 512    // factor rank
#define NTAG 400  // tags
#define NV 20000  // vocab

__device__ __forceinline__ float bfu(u16 u) {
    unsigned x = ((unsigned)u) << 16;
    return __builtin_bit_cast(float, x);
}
__device__ __forceinline__ u16 f2b(float f) {
    unsigned u = __builtin_bit_cast(unsigned, f);
    unsigned r = (u + 0x7FFFu + ((u >> 16) & 1u)) >> 16;
    return (u16)r;
}
__device__ __forceinline__ float ldin(const void* p, long i, int f32) {
    return f32 ? ((const float*)p)[i] : bfu(((const u16*)p)[i]);
}

// Detect input dtype: fp32 data's low halves produce exponent-all-ones bf16
// patterns at p~1/256; true bf16 (scale 0.02) never does.
__global__ __launch_bounds__(256) void k_detect(const void* emb, int* flag) {
    __shared__ int cnt;
    if (threadIdx.x == 0) cnt = 0;
    __syncthreads();
    const u16* p = (const u16*)emb;
    int local = 0;
    for (int i = threadIdx.x; i < 65536; i += 256) {
        if ((p[i] & 0x7F80) == 0x7F80) local++;
    }
    atomicAdd(&cnt, local);
    __syncthreads();
    if (threadIdx.x == 0) *flag = (cnt > 4) ? 1 : 0;
}

// temp2[g][b][r] = sum_t s[b][t]*Wb[g][t][r] ; temp5 likewise with Ub
// Also zeroes the k_rec sync flags (stream-ordered before k_rec).
__global__ __launch_bounds__(256) void k_tags(const void* __restrict__ s,
        const void* __restrict__ Wb, const void* __restrict__ Ub,
        const int* __restrict__ flagp, float* __restrict__ temp2, float* __restrict__ temp5,
        int* __restrict__ flags) {
    if (blockIdx.x == 0 && threadIdx.x < 256) flags[threadIdx.x] = 0;
    int f32 = *flagp;
    int idx = blockIdx.x * 256 + threadIdx.x;      // over 4*NB*NR
    int r = idx & (NR - 1);
    int gb = idx >> 9;
    int b = gb & (NB - 1);
    int g = gb >> 7;
    float a2 = 0.f, a5 = 0.f;
    if (f32) {
        const float* srow = (const float*)s + b * NTAG;
        const float* wb = (const float*)Wb + (long)g * NTAG * NR + r;
        const float* ub = (const float*)Ub + (long)g * NTAG * NR + r;
        for (int t = 0; t < NTAG; t++) {
            float sv = srow[t];
            a2 += sv * wb[(long)t * NR];
            a5 += sv * ub[(long)t * NR];
        }
    } else {
        const u16* srow = (const u16*)s + b * NTAG;
        const u16* wb = (const u16*)Wb + (long)g * NTAG * NR + r;
        const u16* ub = (const u16*)Ub + (long)g * NTAG * NR + r;
        for (int t = 0; t < NTAG; t++) {
            float sv = bfu(srow[t]);
            a2 += sv * bfu(wb[(long)t * NR]);
            a5 += sv * bfu(ub[(long)t * NR]);
        }
    }
    temp2[idx] = a2;
    temp5[idx] = a5;
}

// Transpose + k-panel swizzle to bf16.
// Output layout (uint4-granular): US[((g*64 + kk)*512 + out)] holds 8 bf16,
// element j = U[g][kk*8 + j][out]  (U treated as [gate][in][out] row-major).
// This is exactly the MFMA B-fragment layout: lane (q,l15) of a k-step ks
// reads chunk (g*64 + ks*4 + q)*512 + n as a short8 -> B[k=ks*32+q*8+j][n].
// z = which*4 + g: which 0 -> Ua->UaS, which 1 -> Uc->UcS.
__global__ __launch_bounds__(256) void k_tr(const void* __restrict__ Ua,
        const void* __restrict__ Uc, const int* __restrict__ flagp,
        u16* __restrict__ UaS, u16* __restrict__ UcS) {
    int f32 = *flagp;
    int z = blockIdx.z;
    int which = z >> 2, g = z & 3;
    const void* src = which ? Uc : Ua;
    u16* dst = which ? UcS : UaS;
    __shared__ u16 tile[64][65];
    int i0 = blockIdx.x * 64;   // input (in-dim) row block
    int j0 = blockIdx.y * 64;   // input (out-dim) col block
    int t = threadIdx.x;
    int il = t >> 2, js = (t & 3) * 16;
    long base = ((long)g * 512 + i0 + il) * 512 + j0 + js;
    if (f32) {
        const float* q = (const float*)src + base;
        #pragma unroll
        for (int j = 0; j < 16; j++) tile[il][js + j] = f2b(q[j]);
    } else {
        const u16* q = (const u16*)src + base;
        #pragma unroll
        for (int j = 0; j < 16; j++) tile[il][js + j] = q[j];
    }
    __syncthreads();
    // store: 512 output 16B chunks per tile (8 k-panels x 64 out cols), 2/thread
    #pragma unroll
    for (int h = 0; h < 2; h++) {
        int idx = t + h * 256;
        int kl = idx >> 6, rl = idx & 63;
        u16 outv[8] __attribute__((aligned(16)));
        #pragma unroll
        for (int j = 0; j < 8; j++) outv[j] = tile[kl * 8 + j][rl];
        long ob = ((long)(g * 64 + (i0 >> 3) + kl) * 512 + (j0 + rl)) * 8;
        *(uint4*)(dst + ob) = *(uint4*)outv;
    }
}

// MFMA GEMM, block tile 64(M) x 128(N), K=512, 256 threads (4 waves).
// MODE 0: A = emb-gather (flag dtype), B = Wa[g] (flag), epi: *temp2 -> t1m bf16
// MODE 1: A = t1m[g] bf16, B = Wc[g] (flag), epi: plain -> gx bf16
// MODE 2: A = hs bf16, B = Wout (flag), epi: +bout, swizzle (t,b)->(b,t), guard n<NV
template<int MODE>
__global__ __launch_bounds__(256) void k_mfma(const void* __restrict__ Asrc,
        const void* __restrict__ Bsrc, void* __restrict__ dst,
        const int* __restrict__ captions, const float* __restrict__ temp2,
        const void* __restrict__ bout, const int* __restrict__ flagp) {
    const int f32 = *flagp;
    const int bm = blockIdx.x * 64;
    const int bn = blockIdx.y * 128;
    const int g = blockIdx.z;
    const int NN = (MODE == 2) ? NV : NR;
    const int ldb = (MODE == 2) ? NV : NR;
    __shared__ __align__(16) u16 As[64 * 40];
    __shared__ __align__(16) u16 Bs[32 * 132];
    const int tid = threadIdx.x;
    const int sam = tid >> 2, sak = (tid & 3) * 8;      // A staging: row, k-offset
    const int sbk = tid >> 3, sbn = (tid & 7) * 16;     // B staging: k-row, n-offset
    long arow = 0;
    int azero = 0;
    if (MODE == 0) {
        int mg = bm + sam, tt = mg >> 7, bb = mg & (NB - 1);
        if (tt == 0) azero = 1;
        else arow = (long)captions[bb * NT + tt - 1] * NE;
    } else if (MODE == 1) {
        arow = ((long)g * NT * NB + bm + sam) * NR;
    } else {
        arow = (long)(bm + sam) * NH;
    }
    long bbase;
    if (MODE == 2) bbase = bn + sbn;
    else bbase = (long)g * 512 * 512 + bn + sbn;
    const int bguard = (MODE == 2) && (bn + 128 > NN);

    const int wv = tid >> 6, ln = tid & 63;
    const int q = ln >> 4, l15 = ln & 15;
    floatx4 acc[4][2];
    #pragma unroll
    for (int i = 0; i < 4; i++)
        #pragma unroll
        for (int j = 0; j < 2; j++)
            #pragma unroll
            for (int r = 0; r < 4; r++) acc[i][j][r] = 0.f;

    for (int k0 = 0; k0 < 512; k0 += 32) {
        // ---- stage A (8 elems/thread) ----
        u16 ta[8] __attribute__((aligned(16)));
        if (MODE == 0) {
            if (azero) {
                #pragma unroll
                for (int j = 0; j < 8; j++) ta[j] = 0;
            } else if (f32) {
                const float* qa = (const float*)Asrc + arow + k0 + sak;
                #pragma unroll
                for (int j = 0; j < 8; j++) ta[j] = f2b(qa[j]);
            } else {
                *(uint4*)ta = *(const uint4*)((const u16*)Asrc + arow + k0 + sak);
            }
        } else {
            *(uint4*)ta = *(const uint4*)((const u16*)Asrc + arow + k0 + sak);
        }
        *(uint4*)&As[sam * 40 + sak] = *(uint4*)ta;
        // ---- stage B (16 elems/thread, natural [k][n]) ----
        u16 tb[16] __attribute__((aligned(16)));
        long be = bbase + (long)(k0 + sbk) * ldb;
        if (!bguard) {
            if (f32) {
                const float* qb = (const float*)Bsrc + be;
                #pragma unroll
                for (int j = 0; j < 16; j++) tb[j] = f2b(qb[j]);
            } else {
                *(uint4*)tb = *(const uint4*)((const u16*)Bsrc + be);
                *(uint4*)(tb + 8) = *(const uint4*)((const u16*)Bsrc + be + 8);
            }
        } else {
            #pragma unroll
            for (int j = 0; j < 16; j++) {
                int n = bn + sbn + j;
                tb[j] = (n < NN) ? (f32 ? f2b(((const float*)Bsrc)[be + j])
                                        : ((const u16*)Bsrc)[be + j]) : (u16)0;
            }
        }
        *(uint2*)&Bs[sbk * 132 + sbn]      = *(uint2*)tb;
        *(uint2*)&Bs[sbk * 132 + sbn + 4]  = *(uint2*)(tb + 4);
        *(uint2*)&Bs[sbk * 132 + sbn + 8]  = *(uint2*)(tb + 8);
        *(uint2*)&Bs[sbk * 132 + sbn + 12] = *(uint2*)(tb + 12);
        __syncthreads();
        // ---- fragments + MFMA ----
        short8 af[4];
        #pragma unroll
        for (int mi = 0; mi < 4; mi++)
            af[mi] = *(const short8*)&As[(mi * 16 + l15) * 40 + q * 8];
        #pragma unroll
        for (int ni = 0; ni < 2; ni++) {
            union { u16 u[8]; short8 v; } bu;
            int n = wv * 32 + ni * 16 + l15;
            #pragma unroll
            for (int j = 0; j < 8; j++) bu.u[j] = Bs[(q * 8 + j) * 132 + n];
            #pragma unroll
            for (int mi = 0; mi < 4; mi++)
                acc[mi][ni] = __builtin_amdgcn_mfma_f32_16x16x32_bf16(af[mi], bu.v, acc[mi][ni], 0, 0, 0);
        }
        __syncthreads();
    }
    // ---- epilogue ----
    #pragma unroll
    for (int mi = 0; mi < 4; mi++) {
        #pragma unroll
        for (int ni = 0; ni < 2; ni++) {
            int n = bn + wv * 32 + ni * 16 + l15;
            #pragma unroll
            for (int r = 0; r < 4; r++) {
                int m = bm + mi * 16 + q * 4 + r;
                float v = acc[mi][ni][r];
                if (MODE == 0) {
                    int bb = m & (NB - 1);
                    v *= temp2[((long)g * NB + bb) * NR + n];
                    ((u16*)dst)[((long)g * NT * NB + m) * NR + n] = f2b(v);
                } else if (MODE == 1) {
                    ((u16*)dst)[((long)g * NT * NB + m) * NR + n] = f2b(v);
                } else {
                    if (n < NV) {
                        int tt = m >> 7, bb = m & (NB - 1);
                        float o = v + ldin(bout, n, f32);
                        long oi = ((long)bb * NT + tt) * NV + n;
                        if (f32) ((float*)dst)[oi] = o;
                        else ((u16*)dst)[oi] = f2b(o);
                    }
                }
            }
        }
    }
}

// Recurrence as per-step batched MFMA GEMM, v2.
// 256 blocks = 8 bg(16 rows) x 4 gates x 8 col-slices, 512 thr (8 waves).
// bid = c + 8*g + 32*bg so all blocks with the same c land on one XCD ->
// per-XCD weight footprint (full Ua 2MB + Uc col-slices 256KB) stays L2-resident.
// Phase A (replicated over the 8 c-siblings): t6[g][16][512] = (h @ Ua[g])*t5,
//   MFMA, B-frags direct from k-panel global, A from LDS hb.
// Phase B (waves 0-3): pre[g][16][c*64..+64] = t6 @ Uc[g] slice, published as
//   relaxed agent atomic f32 (parity buffer) + release flag (2t+1).
// Pointwise: block owns h-slice [myid*16, +16): threads<128 read 4 gates x 2
//   cols as u64 agent atomics (4 loads/thread), LSTM, publish h-slice bf16
//   (u32 atomics) + release flag (2t+2). All blocks re-read h (4 u64/thread)
//   into hb LDS. Flags monotonic; parity-lapping safe: a buffer is rewritten
//   at t+2 only after all peers passed flag 2t+4-ish barriers (see r2/r3).
__global__ __launch_bounds__(512) void k_rec(const u16* __restrict__ UaS,
        const u16* __restrict__ UcS, const float* __restrict__ temp5,
        const u16* __restrict__ gx, const void* __restrict__ bias,
        const void* __restrict__ h0, const void* __restrict__ c0,
        const int* __restrict__ flagp, u16* __restrict__ hs,
        float* __restrict__ preX, u64* __restrict__ hX, int* __restrict__ flags) {
    const int f32 = *flagp;
    const int bid = blockIdx.x;
    const int c  = bid & 7;
    const int g  = (bid >> 3) & 3;
    const int bg = bid >> 5;
    const int myid = g * 8 + c;        // 0..31 within batch group
    const int tid = threadIdx.x;
    const int wv = tid >> 6, ln = tid & 63, q = ln >> 4, l15 = ln & 15;

    __shared__ __align__(16) u16 hb[16 * 520];   // h (bf16), A-frag friendly
    __shared__ __align__(16) u16 t6s[16 * 520];  // t6 (bf16)

    // init hb from h0 (all blocks): thread covers (row, 16 cols)
    {
        int row = tid >> 5, col = (tid & 31) * 16;
        #pragma unroll
        for (int j = 0; j < 16; j++)
            hb[row * 520 + col + j] = f2b(ldin(h0, (long)(bg * 16 + row) * NH + col + j, f32));
    }
    // temp5 in phase-A C-fragment layout
    float t5v[4][4];
    #pragma unroll
    for (int nt = 0; nt < 4; nt++)
        #pragma unroll
        for (int r = 0; r < 4; r++)
            t5v[nt][r] = temp5[((long)g * NB + bg * 16 + q * 4 + r) * NR
                               + wv * 64 + nt * 16 + l15];
    // pointwise owner state: tid<128 handles (prow, pcol..pcol+1) of h-slice myid
    const int prow = tid >> 3;
    const int pcol = myid * 16 + (tid & 7) * 2;
    const int bglob = bg * 16 + prow;
    float cs0 = 0.f, cs1 = 0.f;
    float bv[4][2];
    if (tid < 128) {
        cs0 = ldin(c0, (long)bglob * NH + pcol, f32);
        cs1 = ldin(c0, (long)bglob * NH + pcol + 1, f32);
        #pragma unroll
        for (int g4 = 0; g4 < 4; g4++) {
            bv[g4][0] = ldin(bias, g4 * NH + pcol, f32);
            bv[g4][1] = ldin(bias, g4 * NH + pcol + 1, f32);
        }
    }
    int* myFlag = &flags[bg * 32 + myid];
    __syncthreads();

    for (int t = 0; t < NT; t++) {
        const int pr_ = t & 1;
        // ---- phase A: t6 = (h @ Ua[g]) * t5 ; wave covers cols wv*64..+64 ----
        floatx4 accA[4];
        #pragma unroll
        for (int nt = 0; nt < 4; nt++)
            #pragma unroll
            for (int r = 0; r < 4; r++) accA[nt][r] = 0.f;
        const int colA = wv * 64 + l15;
        #pragma unroll 4
        for (int ks = 0; ks < 16; ks++) {
            short8 af = *(const short8*)&hb[l15 * 520 + ks * 32 + q * 8];
            #pragma unroll
            for (int nt = 0; nt < 4; nt++) {
                short8 bf = *(const short8*)(UaS
                    + ((long)(g * 64 + ks * 4 + q) * 512 + colA + nt * 16) * 8);
                accA[nt] = __builtin_amdgcn_mfma_f32_16x16x32_bf16(af, bf, accA[nt], 0, 0, 0);
            }
        }
        #pragma unroll
        for (int nt = 0; nt < 4; nt++)
            #pragma unroll
            for (int r = 0; r < 4; r++)
                t6s[(q * 4 + r) * 520 + colA + nt * 16] = f2b(accA[nt][r] * t5v[nt][r]);
        __syncthreads();
        // ---- phase B (waves 0-3): pre slice = t6 @ Uc[g][:, c*64 + 64] ----
        if (wv < 4) {
            floatx4 accB;
            #pragma unroll
            for (int r = 0; r < 4; r++) accB[r] = 0.f;
            const int colB = c * 64 + wv * 16 + l15;
            #pragma unroll 4
            for (int ks = 0; ks < 16; ks++) {
                short8 af = *(const short8*)&t6s[l15 * 520 + ks * 32 + q * 8];
                short8 bf = *(const short8*)(UcS
                    + ((long)(g * 64 + ks * 4 + q) * 512 + colB) * 8);
                accB = __builtin_amdgcn_mfma_f32_16x16x32_bf16(af, bf, accB, 0, 0, 0);
            }
            float* pbase = preX + (((long)pr_ * 8 + bg) * 4 + g) * 16 * 512;
            #pragma unroll
            for (int r = 0; r < 4; r++)
                __hip_atomic_store(&pbase[(q * 4 + r) * 512 + colB], accB[r],
                                   __ATOMIC_RELAXED, __HIP_MEMORY_SCOPE_AGENT);
        }
        __syncthreads();   // all waves' atomic stores drained (vmcnt0 before barrier)
        if (tid == 0)
            __hip_atomic_store(myFlag, 2 * t + 1, __ATOMIC_RELEASE, __HIP_MEMORY_SCOPE_AGENT);
        if (tid < 32)
            while (__hip_atomic_load(&flags[bg * 32 + tid], __ATOMIC_RELAXED,
                                     __HIP_MEMORY_SCOPE_AGENT) < 2 * t + 1)
                __builtin_amdgcn_s_sleep(1);
        __syncthreads();
        __builtin_amdgcn_fence(__ATOMIC_ACQUIRE, "workgroup");  // compiler barrier, no L2 inv
        // ---- pointwise (owners: tid<128, 2 LSTM cells each) ----
        if (tid < 128) {
            float pv[4][2];
            #pragma unroll
            for (int g4 = 0; g4 < 4; g4++) {
                u64 uu = __hip_atomic_load((u64*)(preX
                         + ((((long)pr_ * 8 + bg) * 4 + g4) * 16 + prow) * 512 + pcol),
                         __ATOMIC_RELAXED, __HIP_MEMORY_SCOPE_AGENT);
                unsigned gxp = *(const unsigned*)&gx[(((long)g4 * NT + t) * NB + bglob) * NH + pcol];
                pv[g4][0] = __builtin_bit_cast(float, (unsigned)(uu & 0xFFFFFFFFu))
                            + bfu((u16)(gxp & 0xFFFFu)) + bv[g4][0];
                pv[g4][1] = __builtin_bit_cast(float, (unsigned)(uu >> 32))
                            + bfu((u16)(gxp >> 16)) + bv[g4][1];
            }
            float i0 = 1.f / (1.f + expf(-pv[0][0]));
            float f0 = 1.f / (1.f + expf(-pv[1][0]));
            float o0 = 1.f / (1.f + expf(-pv[2][0]));
            float ct0 = tanhf(pv[3][0]);
            float cn0 = f0 * cs0 + i0 * ct0;
            float hn0 = o0 * tanhf(cn0);
            cs0 = cn0;
            float i1 = 1.f / (1.f + expf(-pv[0][1]));
            float f1 = 1.f / (1.f + expf(-pv[1][1]));
            float o1 = 1.f / (1.f + expf(-pv[2][1]));
            float ct1 = tanhf(pv[3][1]);
            float cn1 = f1 * cs1 + i1 * ct1;
            float hn1 = o1 * tanhf(cn1);
            cs1 = cn1;
            unsigned hpack = (unsigned)f2b(hn0) | ((unsigned)f2b(hn1) << 16);
            __hip_atomic_store((unsigned*)hX
                               + (((long)pr_ * 8 + bg) * 16 + prow) * 256 + (pcol >> 1),
                               hpack, __ATOMIC_RELAXED, __HIP_MEMORY_SCOPE_AGENT);
            *(unsigned*)&hs[((long)t * NB + bglob) * NH + pcol] = hpack;
        }
        __syncthreads();
        if (tid == 0)
            __hip_atomic_store(myFlag, 2 * t + 2, __ATOMIC_RELEASE, __HIP_MEMORY_SCOPE_AGENT);
        if (tid < 32)
            while (__hip_atomic_load(&flags[bg * 32 + tid], __ATOMIC_RELAXED,
                                     __HIP_MEMORY_SCOPE_AGENT) < 2 * t + 2)
                __builtin_amdgcn_s_sleep(1);
        __syncthreads();
        __builtin_amdgcn_fence(__ATOMIC_ACQUIRE, "workgroup");
        // ---- reload hb from hX (4 u64 agent atomics/thread) ----
        {
            int row = tid >> 5, col = (tid & 31) * 16;
            u64 vv[4];
            #pragma unroll
            for (int j = 0; j < 4; j++)
                vv[j] = __hip_atomic_load(hX + (((long)pr_ * 8 + bg) * 16 + row) * 128
                                          + (col >> 2) + j,
                                          __ATOMIC_RELAXED, __HIP_MEMORY_SCOPE_AGENT);
            u16 tmp[16] __attribute__((aligned(16)));
            #pragma unroll
            for (int j = 0; j < 4; j++) *(u64*)&tmp[j * 4] = vv[j];
            *(uint4*)&hb[row * 520 + col] = *(uint4*)tmp;
            *(uint4*)&hb[row * 520 + col + 8] = *(uint4*)(tmp + 8);
        }
        __syncthreads();
    }
}

extern "C" void kernel_launch(void* const* d_in, const int* in_sizes, int n_in,
                              void* d_out, int out_size, void* d_ws, size_t ws_size,
                              hipStream_t stream) {
    const int* captions = (const int*)d_in[0];
    const void* s    = d_in[1];
    const void* h0   = d_in[2];
    const void* c0   = d_in[3];
    const void* Wa   = d_in[4];
    const void* Wb   = d_in[5];
    const void* Wc   = d_in[6];
    const void* Ua   = d_in[7];
    const void* Ub   = d_in[8];
    const void* Uc   = d_in[9];
    const void* bias = d_in[10];
    const void* emb  = d_in[11];
    const void* Wout = d_in[12];
    const void* bout = d_in[13];

    // workspace (~33.6 MB)
    char* w = (char*)d_ws;
    int*   flag  = (int*)w;                                  // 256 B
    int*   flags = (int*)(w + 256);                          // 1 KB (256 ints)
    float* temp2 = (float*)(w + 2048);                       // 1 MB
    float* temp5 = temp2 + 4 * NB * NR;                      // 1 MB
    u16*   UaS   = (u16*)(temp5 + 4 * NB * NR);              // 2 MB bf16 (k-panel)
    u16*   UcS   = UaS + 4 * 512 * 512;                      // 2 MB bf16 (k-panel)
    u16*   t1m   = UcS + 4 * 512 * 512;                      // 12.6 MB bf16
    u16*   gx    = t1m + (long)4 * NT * NB * NR;             // 12.6 MB bf16
    float* preX  = (float*)(gx + (long)4 * NT * NB * NR);    // 2 MB (parity dbuf)
    u64*   hX    = (u64*)(preX + 2L * 8 * 4 * 16 * 512);     // 256 KB (parity dbuf)
    u16*   hs    = t1m;  // alias: t1m dead after k_mfma<1>

    dim3 blk(256);
    k_detect<<<1, blk, 0, stream>>>(emb, flag);
    k_tags<<<(4 * NB * NR) / 256, blk, 0, stream>>>(s, Wb, Ub, flag, temp2, temp5, flags);
    k_tr<<<dim3(8, 8, 8), blk, 0, stream>>>(Ua, Uc, flag, UaS, UcS);

    // hoisted input path (MFMA)
    k_mfma<0><<<dim3(48, 4, 4), blk, 0, stream>>>(emb, Wa, t1m, captions, temp2, nullptr, flag);
    k_mfma<1><<<dim3(48, 4, 4), blk, 0, stream>>>(t1m, Wc, gx, nullptr, nullptr, nullptr, flag);

    // fused recurrence: 256 blocks (8 bg x 4 g x 8 c), MFMA + 2 handshakes/step
    k_rec<<<256, 512, 0, stream>>>(UaS, UcS, temp5, gx, bias, h0, c0, flag, hs, preX, hX, flags);

    // output projection (MFMA), grid.x = M-tiles so consecutive blocks share W strip in L2
    k_mfma<2><<<dim3(48, 157, 1), blk, 0, stream>>>(hs, Wout, d_out, nullptr, nullptr, bout, flag);
}